// Round 1
// baseline (290.128 us; speedup 1.0000x reference)
//
#include <hip/hip_runtime.h>

// PhraseClassifier: gather fwd/bwd half-rows, dot with W, sigmoid+BCE, mean.
// hidden: (2048, 16, 1024) f32; spans: 200000; out: 1 f32 scalar.

#define HIDD 512
#define FEAT 1024
#define NWARPS_PER_BLOCK 4

__global__ __launch_bounds__(256) void phrase_cls_kernel(
    const float* __restrict__ hidden,
    const int*   __restrict__ bids,
    const int*   __restrict__ begins,
    const int*   __restrict__ ends,
    const float* __restrict__ targets,
    const float* __restrict__ W,
    const float* __restrict__ bias_p,
    float*       __restrict__ out,
    int nspans, float inv_n)
{
    const int lane  = threadIdx.x & 63;
    const int wid   = threadIdx.x >> 6;               // wave in block, 0..3
    const int gwave = blockIdx.x * NWARPS_PER_BLOCK + wid;
    const int nwaves = gridDim.x * NWARPS_PER_BLOCK;

    // Preload this lane's W fragments (constant across spans).
    // Pass p of fwd half covers floats (p*64+lane)*4 .. +3; bwd half is +512.
    const float4* W4 = reinterpret_cast<const float4*>(W);
    const float4 w0 = W4[lane];          // fwd pass 0
    const float4 w1 = W4[64 + lane];     // fwd pass 1
    const float4 w2 = W4[128 + lane];    // bwd pass 0
    const float4 w3 = W4[192 + lane];    // bwd pass 1
    const float bias = bias_p[0];

    float acc = 0.0f;

    for (int s = gwave; s < nspans; s += nwaves) {
        const int   bid = bids[s];
        const int   beg = begins[s] - 1;
        const int   end = ends[s];
        const float t   = targets[s];

        const float4* frow = reinterpret_cast<const float4*>(
            hidden + ((size_t)beg * 16 + (size_t)bid) * FEAT);
        const float4* brow = reinterpret_cast<const float4*>(
            hidden + ((size_t)end * 16 + (size_t)bid) * FEAT + HIDD);

        const float4 a0 = frow[lane];
        const float4 a1 = frow[64 + lane];
        const float4 a2 = brow[lane];
        const float4 a3 = brow[64 + lane];

        float d = a0.x * w0.x + a0.y * w0.y + a0.z * w0.z + a0.w * w0.w
                + a1.x * w1.x + a1.y * w1.y + a1.z * w1.z + a1.w * w1.w
                + a2.x * w2.x + a2.y * w2.y + a2.z * w2.z + a2.w * w2.w
                + a3.x * w3.x + a3.y * w3.y + a3.z * w3.z + a3.w * w3.w;

        // Wave-64 butterfly reduce.
        #pragma unroll
        for (int off = 32; off >= 1; off >>= 1)
            d += __shfl_xor(d, off, 64);

        if (lane == 0) {
            const float z  = d + bias;
            const float p  = 1.0f / (1.0f + expf(-z));
            const float pc = fminf(fmaxf(p, 1e-12f), 1.0f);
            const float qc = fminf(fmaxf(1.0f - p, 1e-12f), 1.0f);
            const float bce = -(t * logf(pc) + (1.0f - t) * logf(qc));
            acc += bce;
        }
    }

    __shared__ float sacc[NWARPS_PER_BLOCK];
    if (lane == 0) sacc[wid] = acc;
    __syncthreads();
    if (threadIdx.x == 0) {
        float ssum = 0.0f;
        #pragma unroll
        for (int i = 0; i < NWARPS_PER_BLOCK; ++i) ssum += sacc[i];
        atomicAdd(out, ssum * inv_n);
    }
}

extern "C" void kernel_launch(void* const* d_in, const int* in_sizes, int n_in,
                              void* d_out, int out_size, void* d_ws, size_t ws_size,
                              hipStream_t stream) {
    const float* hidden  = (const float*)d_in[0];
    const int*   bids    = (const int*)  d_in[1];
    const int*   begins  = (const int*)  d_in[2];
    const int*   ends    = (const int*)  d_in[3];
    const float* targets = (const float*)d_in[4];
    const float* W       = (const float*)d_in[5];
    const float* b       = (const float*)d_in[6];
    float* out = (float*)d_out;

    const int nspans = in_sizes[1];

    // Harness poisons d_out with 0xAA before every launch; zero it first.
    hipMemsetAsync(out, 0, sizeof(float), stream);

    const int blocks = 2048;  // 8 blocks/CU, 32 waves/CU occupancy
    phrase_cls_kernel<<<blocks, 256, 0, stream>>>(
        hidden, bids, begins, ends, targets, W, b, out,
        nspans, 1.0f / (float)nspans);
}

// Round 2
// 214.200 us; speedup vs baseline: 1.3545x; 1.3545x over previous
//
#include <hip/hip_runtime.h>

// PhraseClassifier, two-phase:
//   K1: fwd/bwd half-row dot-products over ALL (pos,bid) rows -> table (256KB)
//   K2: per-span table lookup + sigmoid + BCE + mean reduce
// hidden: (2048, 16, 1024) f32; spans: 200000; out: 1 f32 scalar.

#define HIDD 512
#define FEAT 1024
#define NROWS (2048 * 16)
#define NWAVES_PER_BLOCK 4

__device__ __forceinline__ float dot4(float4 a, float4 w) {
    return a.x * w.x + a.y * w.y + a.z * w.z + a.w * w.w;
}

// ---------------- Kernel 1: row dot table ----------------
__global__ __launch_bounds__(256) void row_dot_kernel(
    const float* __restrict__ hidden,
    const float* __restrict__ W,
    float*       __restrict__ tab,     // [2*NROWS]: fwd dots then bwd dots
    int nrows)
{
    const int lane  = threadIdx.x & 63;
    const int wid   = threadIdx.x >> 6;
    const int gwave = blockIdx.x * NWAVES_PER_BLOCK + wid;
    const int nwaves = gridDim.x * NWAVES_PER_BLOCK;

    const float4* W4 = reinterpret_cast<const float4*>(W);
    const float4 w0 = W4[lane];
    const float4 w1 = W4[64 + lane];
    const float4 w2 = W4[128 + lane];
    const float4 w3 = W4[192 + lane];

    for (int row = gwave; row < nrows; row += nwaves) {
        const float4* r = reinterpret_cast<const float4*>(hidden + (size_t)row * FEAT);
        const float4 a0 = r[lane];
        const float4 a1 = r[64 + lane];
        const float4 a2 = r[128 + lane];
        const float4 a3 = r[192 + lane];

        float df = dot4(a0, w0) + dot4(a1, w1);
        float db = dot4(a2, w2) + dot4(a3, w3);

        #pragma unroll
        for (int off = 32; off >= 1; off >>= 1) {
            df += __shfl_xor(df, off, 64);
            db += __shfl_xor(db, off, 64);
        }
        if (lane == 0) {
            tab[row] = df;
            tab[nrows + row] = db;
        }
    }
}

// ---------------- Kernel 2: span lookup + BCE ----------------
__global__ __launch_bounds__(256) void span_bce_kernel(
    const float* __restrict__ tab,
    const int*   __restrict__ bids,
    const int*   __restrict__ begins,
    const int*   __restrict__ ends,
    const float* __restrict__ targets,
    const float* __restrict__ bias_p,
    float*       __restrict__ out,
    int nspans, float inv_n, int nrows)
{
    const float bias = bias_p[0];
    float acc = 0.0f;

    for (int i = blockIdx.x * blockDim.x + threadIdx.x; i < nspans;
         i += gridDim.x * blockDim.x) {
        const int   bid = bids[i];
        const int   fr  = (begins[i] - 1) * 16 + bid;
        const int   br  = ends[i] * 16 + bid;
        const float t   = targets[i];

        const float z  = tab[fr] + tab[nrows + br] + bias;
        const float p  = 1.0f / (1.0f + expf(-z));
        const float pc = fminf(fmaxf(p, 1e-12f), 1.0f);
        const float qc = fminf(fmaxf(1.0f - p, 1e-12f), 1.0f);
        acc += -(t * logf(pc) + (1.0f - t) * logf(qc));
    }

    // wave reduce
    #pragma unroll
    for (int off = 32; off >= 1; off >>= 1)
        acc += __shfl_xor(acc, off, 64);

    __shared__ float sacc[NWAVES_PER_BLOCK];
    const int lane = threadIdx.x & 63;
    const int wid  = threadIdx.x >> 6;
    if (lane == 0) sacc[wid] = acc;
    __syncthreads();
    if (threadIdx.x == 0) {
        float s = 0.0f;
        #pragma unroll
        for (int i = 0; i < NWAVES_PER_BLOCK; ++i) s += sacc[i];
        atomicAdd(out, s * inv_n);
    }
}

// ---------------- Fallback (round-1 single kernel) ----------------
__global__ __launch_bounds__(256) void phrase_cls_fallback(
    const float* __restrict__ hidden,
    const int*   __restrict__ bids,
    const int*   __restrict__ begins,
    const int*   __restrict__ ends,
    const float* __restrict__ targets,
    const float* __restrict__ W,
    const float* __restrict__ bias_p,
    float*       __restrict__ out,
    int nspans, float inv_n)
{
    const int lane  = threadIdx.x & 63;
    const int wid   = threadIdx.x >> 6;
    const int gwave = blockIdx.x * NWAVES_PER_BLOCK + wid;
    const int nwaves = gridDim.x * NWAVES_PER_BLOCK;

    const float4* W4 = reinterpret_cast<const float4*>(W);
    const float4 w0 = W4[lane];
    const float4 w1 = W4[64 + lane];
    const float4 w2 = W4[128 + lane];
    const float4 w3 = W4[192 + lane];
    const float bias = bias_p[0];

    float acc = 0.0f;
    for (int s = gwave; s < nspans; s += nwaves) {
        const int   bid = bids[s];
        const int   beg = begins[s] - 1;
        const int   end = ends[s];
        const float t   = targets[s];
        const float4* frow = reinterpret_cast<const float4*>(
            hidden + ((size_t)beg * 16 + (size_t)bid) * FEAT);
        const float4* brow = reinterpret_cast<const float4*>(
            hidden + ((size_t)end * 16 + (size_t)bid) * FEAT + HIDD);
        float d = dot4(frow[lane], w0) + dot4(frow[64 + lane], w1)
                + dot4(brow[lane], w2) + dot4(brow[64 + lane], w3);
        #pragma unroll
        for (int off = 32; off >= 1; off >>= 1)
            d += __shfl_xor(d, off, 64);
        if (lane == 0) {
            const float z  = d + bias;
            const float p  = 1.0f / (1.0f + expf(-z));
            const float pc = fminf(fmaxf(p, 1e-12f), 1.0f);
            const float qc = fminf(fmaxf(1.0f - p, 1e-12f), 1.0f);
            acc += -(t * logf(pc) + (1.0f - t) * logf(qc));
        }
    }
    __shared__ float sacc[NWAVES_PER_BLOCK];
    if (lane == 0) sacc[wid] = acc;
    __syncthreads();
    if (threadIdx.x == 0) {
        float s = 0.0f;
        #pragma unroll
        for (int i = 0; i < NWAVES_PER_BLOCK; ++i) s += sacc[i];
        atomicAdd(out, s * inv_n);
    }
}

extern "C" void kernel_launch(void* const* d_in, const int* in_sizes, int n_in,
                              void* d_out, int out_size, void* d_ws, size_t ws_size,
                              hipStream_t stream) {
    const float* hidden  = (const float*)d_in[0];
    const int*   bids    = (const int*)  d_in[1];
    const int*   begins  = (const int*)  d_in[2];
    const int*   ends    = (const int*)  d_in[3];
    const float* targets = (const float*)d_in[4];
    const float* W       = (const float*)d_in[5];
    const float* b       = (const float*)d_in[6];
    float* out = (float*)d_out;

    const int nspans = in_sizes[1];
    const float inv_n = 1.0f / (float)nspans;

    hipMemsetAsync(out, 0, sizeof(float), stream);

    const size_t tab_bytes = (size_t)2 * NROWS * sizeof(float);
    if (ws_size >= tab_bytes) {
        float* tab = (float*)d_ws;
        // K1: 32768 rows, 4 waves/block, grid-stride (2 rows/wave at 4096 blocks)
        row_dot_kernel<<<4096, 256, 0, stream>>>(hidden, W, tab, NROWS);
        // K2: one thread per span
        const int blocks2 = (nspans + 255) / 256;
        span_bce_kernel<<<blocks2, 256, 0, stream>>>(
            tab, bids, begins, ends, targets, b, out, nspans, inv_n, NROWS);
    } else {
        phrase_cls_fallback<<<2048, 256, 0, stream>>>(
            hidden, bids, begins, ends, targets, W, b, out, nspans, inv_n);
    }
}

// Round 3
// 210.106 us; speedup vs baseline: 1.3809x; 1.0195x over previous
//
#include <hip/hip_runtime.h>

// PhraseClassifier, three-phase, atomic-free:
//   K1: fwd/bwd half-row dots over all (pos,bid) rows -> tab (256KB in ws)
//   K2: per-span lookup + sigmoid + BCE -> per-block partial sums (in ws)
//   K3: reduce partials -> out[0] (direct write, no memset needed)
// hidden: (2048, 16, 1024) f32; spans: 200000; out: 1 f32 scalar.

#define HIDD 512
#define FEAT 1024
#define NROWS (2048 * 16)
#define NWAVES_PER_BLOCK 4
#define K2_BLOCK 256

__device__ __forceinline__ float dot4(float4 a, float4 w) {
    return a.x * w.x + a.y * w.y + a.z * w.z + a.w * w.w;
}

__device__ __forceinline__ float wave_reduce(float v) {
    #pragma unroll
    for (int off = 32; off >= 1; off >>= 1)
        v += __shfl_xor(v, off, 64);
    return v;
}

// ---------------- Kernel 1: row dot table (2 rows/iter for MLP) ----------------
__global__ __launch_bounds__(256) void row_dot_kernel(
    const float* __restrict__ hidden,
    const float* __restrict__ W,
    float*       __restrict__ tab,     // [2*NROWS]: fwd dots then bwd dots
    int nrows)
{
    const int lane  = threadIdx.x & 63;
    const int wid   = threadIdx.x >> 6;
    const int gwave = blockIdx.x * NWAVES_PER_BLOCK + wid;
    const int nwaves = gridDim.x * NWAVES_PER_BLOCK;

    const float4* W4 = reinterpret_cast<const float4*>(W);
    const float4 w0 = W4[lane];
    const float4 w1 = W4[64 + lane];
    const float4 w2 = W4[128 + lane];
    const float4 w3 = W4[192 + lane];

    // Two rows per iteration: 8 independent dwordx4 loads in flight.
    for (int row = gwave * 2; row < nrows; row += nwaves * 2) {
        const float4* r0 = reinterpret_cast<const float4*>(hidden + (size_t)row * FEAT);
        const float4* r1 = reinterpret_cast<const float4*>(hidden + (size_t)(row + 1) * FEAT);

        const float4 a0 = r0[lane];
        const float4 a1 = r0[64 + lane];
        const float4 a2 = r0[128 + lane];
        const float4 a3 = r0[192 + lane];
        const float4 b0 = r1[lane];
        const float4 b1 = r1[64 + lane];
        const float4 b2 = r1[128 + lane];
        const float4 b3 = r1[192 + lane];

        float df0 = dot4(a0, w0) + dot4(a1, w1);
        float db0 = dot4(a2, w2) + dot4(a3, w3);
        float df1 = dot4(b0, w0) + dot4(b1, w1);
        float db1 = dot4(b2, w2) + dot4(b3, w3);

        df0 = wave_reduce(df0);
        db0 = wave_reduce(db0);
        df1 = wave_reduce(df1);
        db1 = wave_reduce(db1);

        if (lane == 0) {
            tab[row]             = df0;
            tab[row + 1]         = df1;
            tab[nrows + row]     = db0;
            tab[nrows + row + 1] = db1;
        }
    }
}

// ---------------- Kernel 2: span lookup + BCE -> block partials ----------------
__global__ __launch_bounds__(K2_BLOCK) void span_bce_kernel(
    const float* __restrict__ tab,
    const int*   __restrict__ bids,
    const int*   __restrict__ begins,
    const int*   __restrict__ ends,
    const float* __restrict__ targets,
    const float* __restrict__ bias_p,
    float*       __restrict__ partials,
    int nspans, int nrows)
{
    const float bias = bias_p[0];
    float acc = 0.0f;

    const int i = blockIdx.x * K2_BLOCK + threadIdx.x;
    if (i < nspans) {
        const int   bid = bids[i];
        const int   fr  = (begins[i] - 1) * 16 + bid;
        const int   br  = ends[i] * 16 + bid;
        const float t   = targets[i];

        const float z  = tab[fr] + tab[nrows + br] + bias;
        const float p  = 1.0f / (1.0f + expf(-z));
        const float pc = fminf(fmaxf(p, 1e-12f), 1.0f);
        const float qc = fminf(fmaxf(1.0f - p, 1e-12f), 1.0f);
        acc = -(t * logf(pc) + (1.0f - t) * logf(qc));
    }

    acc = wave_reduce(acc);

    __shared__ float sacc[K2_BLOCK / 64];
    const int lane = threadIdx.x & 63;
    const int wid  = threadIdx.x >> 6;
    if (lane == 0) sacc[wid] = acc;
    __syncthreads();
    if (threadIdx.x == 0) {
        float s = 0.0f;
        #pragma unroll
        for (int k = 0; k < K2_BLOCK / 64; ++k) s += sacc[k];
        partials[blockIdx.x] = s;
    }
}

// ---------------- Kernel 3: reduce partials -> out ----------------
__global__ __launch_bounds__(256) void final_reduce_kernel(
    const float* __restrict__ partials,
    float*       __restrict__ out,
    int n, float inv_n)
{
    float acc = 0.0f;
    for (int i = threadIdx.x; i < n; i += 256)
        acc += partials[i];
    acc = wave_reduce(acc);

    __shared__ float sacc[4];
    const int lane = threadIdx.x & 63;
    const int wid  = threadIdx.x >> 6;
    if (lane == 0) sacc[wid] = acc;
    __syncthreads();
    if (threadIdx.x == 0)
        out[0] = (sacc[0] + sacc[1] + sacc[2] + sacc[3]) * inv_n;
}

// ---------------- Fallback (round-1 single kernel) ----------------
__global__ __launch_bounds__(256) void phrase_cls_fallback(
    const float* __restrict__ hidden,
    const int*   __restrict__ bids,
    const int*   __restrict__ begins,
    const int*   __restrict__ ends,
    const float* __restrict__ targets,
    const float* __restrict__ W,
    const float* __restrict__ bias_p,
    float*       __restrict__ out,
    int nspans, float inv_n)
{
    const int lane  = threadIdx.x & 63;
    const int wid   = threadIdx.x >> 6;
    const int gwave = blockIdx.x * NWAVES_PER_BLOCK + wid;
    const int nwaves = gridDim.x * NWAVES_PER_BLOCK;

    const float4* W4 = reinterpret_cast<const float4*>(W);
    const float4 w0 = W4[lane];
    const float4 w1 = W4[64 + lane];
    const float4 w2 = W4[128 + lane];
    const float4 w3 = W4[192 + lane];
    const float bias = bias_p[0];

    float acc = 0.0f;
    for (int s = gwave; s < nspans; s += nwaves) {
        const int   bid = bids[s];
        const int   beg = begins[s] - 1;
        const int   end = ends[s];
        const float t   = targets[s];
        const float4* frow = reinterpret_cast<const float4*>(
            hidden + ((size_t)beg * 16 + (size_t)bid) * FEAT);
        const float4* brow = reinterpret_cast<const float4*>(
            hidden + ((size_t)end * 16 + (size_t)bid) * FEAT + HIDD);
        float d = dot4(frow[lane], w0) + dot4(frow[64 + lane], w1)
                + dot4(brow[lane], w2) + dot4(brow[64 + lane], w3);
        d = wave_reduce(d);
        if (lane == 0) {
            const float z  = d + bias;
            const float p  = 1.0f / (1.0f + expf(-z));
            const float pc = fminf(fmaxf(p, 1e-12f), 1.0f);
            const float qc = fminf(fmaxf(1.0f - p, 1e-12f), 1.0f);
            acc += -(t * logf(pc) + (1.0f - t) * logf(qc));
        }
    }
    __shared__ float sacc[NWAVES_PER_BLOCK];
    if (lane == 0) sacc[wid] = acc;
    __syncthreads();
    if (threadIdx.x == 0) {
        float s = 0.0f;
        #pragma unroll
        for (int i = 0; i < NWAVES_PER_BLOCK; ++i) s += sacc[i];
        atomicAdd(out, s * inv_n);
    }
}

extern "C" void kernel_launch(void* const* d_in, const int* in_sizes, int n_in,
                              void* d_out, int out_size, void* d_ws, size_t ws_size,
                              hipStream_t stream) {
    const float* hidden  = (const float*)d_in[0];
    const int*   bids    = (const int*)  d_in[1];
    const int*   begins  = (const int*)  d_in[2];
    const int*   ends    = (const int*)  d_in[3];
    const float* targets = (const float*)d_in[4];
    const float* W       = (const float*)d_in[5];
    const float* b       = (const float*)d_in[6];
    float* out = (float*)d_out;

    const int nspans = in_sizes[1];
    const float inv_n = 1.0f / (float)nspans;
    const int blocks2 = (nspans + K2_BLOCK - 1) / K2_BLOCK;

    const size_t need = ((size_t)2 * NROWS + (size_t)blocks2) * sizeof(float);
    if (ws_size >= need) {
        float* tab      = (float*)d_ws;
        float* partials = tab + 2 * NROWS;
        // K1: 2048 blocks (fully resident), 2 rows per wave-iteration
        row_dot_kernel<<<2048, 256, 0, stream>>>(hidden, W, tab, NROWS);
        // K2: one thread per span, block partials (no atomics)
        span_bce_kernel<<<blocks2, K2_BLOCK, 0, stream>>>(
            tab, bids, begins, ends, targets, b, partials, nspans, NROWS);
        // K3: single block reduces partials, writes out directly
        final_reduce_kernel<<<1, 256, 0, stream>>>(partials, out, blocks2, inv_n);
    } else {
        hipMemsetAsync(out, 0, sizeof(float), stream);
        phrase_cls_fallback<<<2048, 256, 0, stream>>>(
            hidden, bids, begins, ends, targets, W, b, out, nspans, inv_n);
    }
}

// Round 4
// 205.206 us; speedup vs baseline: 1.4138x; 1.0239x over previous
//
#include <hip/hip_runtime.h>

// PhraseClassifier, three-phase, atomic-free:
//   K1: fwd/bwd half-row dots over all (pos,bid) rows -> tab (256KB in ws)
//       exact grid, 2 rows/wave, 7-shfl lane-specialized reduce
//   K2: per-span lookup + sigmoid + BCE -> per-block partial sums (in ws)
//   K3: reduce partials -> out[0]
// hidden: (2048, 16, 1024) f32; spans: 200000; out: 1 f32 scalar.

#define HIDD 512
#define FEAT 1024
#define NROWS (2048 * 16)
#define K2_BLOCK 256

__device__ __forceinline__ float dot4(float4 a, float4 w) {
    return a.x * w.x + a.y * w.y + a.z * w.z + a.w * w.w;
}

__device__ __forceinline__ float wave_reduce(float v) {
    #pragma unroll
    for (int off = 32; off >= 1; off >>= 1)
        v += __shfl_xor(v, off, 64);
    return v;
}

// ---------------- Kernel 1: row dot table ----------------
// 4096 blocks x 256 threads = 16384 waves; each wave: rows [2g, 2g+1].
__global__ __launch_bounds__(256) void row_dot_kernel(
    const float* __restrict__ hidden,
    const float* __restrict__ W,
    float*       __restrict__ tab,     // [2*NROWS]: fwd dots then bwd dots
    int nrows)
{
    const int lane  = threadIdx.x & 63;
    const int wid   = threadIdx.x >> 6;
    const int gwave = blockIdx.x * 4 + wid;
    const int row   = gwave * 2;
    if (row >= nrows) return;

    const float4* W4 = reinterpret_cast<const float4*>(W);
    const float4 w0 = W4[lane];
    const float4 w1 = W4[64 + lane];
    const float4 w2 = W4[128 + lane];
    const float4 w3 = W4[192 + lane];

    const float4* r0 = reinterpret_cast<const float4*>(hidden + (size_t)row * FEAT);
    const float4* r1 = reinterpret_cast<const float4*>(hidden + (size_t)(row + 1) * FEAT);

    // 8 independent dwordx4 loads, all issued before any use.
    const float4 a0 = r0[lane];
    const float4 a1 = r0[64 + lane];
    const float4 a2 = r0[128 + lane];
    const float4 a3 = r0[192 + lane];
    const float4 b0 = r1[lane];
    const float4 b1 = r1[64 + lane];
    const float4 b2 = r1[128 + lane];
    const float4 b3 = r1[192 + lane];

    // v0 = fwd dot row, v2 = fwd dot row+1, v1 = bwd dot row, v3 = bwd dot row+1
    const float v0 = dot4(a0, w0) + dot4(a1, w1);
    const float v1 = dot4(a2, w2) + dot4(a3, w3);
    const float v2 = dot4(b0, w0) + dot4(b1, w1);
    const float v3 = dot4(b2, w2) + dot4(b3, w3);

    // Lane-specialized 4-value reduce: 7 shfls total.
    // Stage 1 (xor 1): fold {v0,v2} by bit0, {v1,v3} by bit0.
    const bool s0 = (lane & 1) != 0;
    float x = s0 ? v2 : v0;
    float y = s0 ? v0 : v2;
    x += __shfl_xor(y, 1, 64);
    float u = s0 ? v3 : v1;
    float w_ = s0 ? v1 : v3;
    u += __shfl_xor(w_, 1, 64);

    // Stage 2 (xor 2): fold {x,u} by bit1.
    const bool s1 = (lane & 2) != 0;
    float p = s1 ? u : x;
    float q = s1 ? x : u;
    p += __shfl_xor(q, 2, 64);

    // Stages 3-6: plain butterfly over remaining 16 groups of 4 lanes.
    p += __shfl_xor(p, 4, 64);
    p += __shfl_xor(p, 8, 64);
    p += __shfl_xor(p, 16, 64);
    p += __shfl_xor(p, 32, 64);

    // lane0=fwd(row), lane1=fwd(row+1), lane2=bwd(row), lane3=bwd(row+1)
    if (lane < 4) {
        const int idx = (lane & 2) ? (nrows + row + (lane & 1)) : (row + (lane & 1));
        tab[idx] = p;
    }
}

// ---------------- Kernel 2: span lookup + BCE -> block partials ----------------
__global__ __launch_bounds__(K2_BLOCK) void span_bce_kernel(
    const float* __restrict__ tab,
    const int*   __restrict__ bids,
    const int*   __restrict__ begins,
    const int*   __restrict__ ends,
    const float* __restrict__ targets,
    const float* __restrict__ bias_p,
    float*       __restrict__ partials,
    int nspans, int nrows)
{
    const float bias = bias_p[0];
    float acc = 0.0f;

    const int i = blockIdx.x * K2_BLOCK + threadIdx.x;
    if (i < nspans) {
        const int   bid = bids[i];
        const int   fr  = (begins[i] - 1) * 16 + bid;
        const int   br  = ends[i] * 16 + bid;
        const float t   = targets[i];

        const float z  = tab[fr] + tab[nrows + br] + bias;
        const float p  = 1.0f / (1.0f + expf(-z));
        const float pc = fminf(fmaxf(p, 1e-12f), 1.0f);
        const float qc = fminf(fmaxf(1.0f - p, 1e-12f), 1.0f);
        acc = -(t * logf(pc) + (1.0f - t) * logf(qc));
    }

    acc = wave_reduce(acc);

    __shared__ float sacc[K2_BLOCK / 64];
    const int lane = threadIdx.x & 63;
    const int wid  = threadIdx.x >> 6;
    if (lane == 0) sacc[wid] = acc;
    __syncthreads();
    if (threadIdx.x == 0) {
        float s = 0.0f;
        #pragma unroll
        for (int k = 0; k < K2_BLOCK / 64; ++k) s += sacc[k];
        partials[blockIdx.x] = s;
    }
}

// ---------------- Kernel 3: reduce partials -> out ----------------
__global__ __launch_bounds__(256) void final_reduce_kernel(
    const float* __restrict__ partials,
    float*       __restrict__ out,
    int n, float inv_n)
{
    float acc = 0.0f;
    for (int i = threadIdx.x; i < n; i += 256)
        acc += partials[i];
    acc = wave_reduce(acc);

    __shared__ float sacc[4];
    const int lane = threadIdx.x & 63;
    const int wid  = threadIdx.x >> 6;
    if (lane == 0) sacc[wid] = acc;
    __syncthreads();
    if (threadIdx.x == 0)
        out[0] = (sacc[0] + sacc[1] + sacc[2] + sacc[3]) * inv_n;
}

// ---------------- Fallback (round-1 single kernel) ----------------
__global__ __launch_bounds__(256) void phrase_cls_fallback(
    const float* __restrict__ hidden,
    const int*   __restrict__ bids,
    const int*   __restrict__ begins,
    const int*   __restrict__ ends,
    const float* __restrict__ targets,
    const float* __restrict__ W,
    const float* __restrict__ bias_p,
    float*       __restrict__ out,
    int nspans, float inv_n)
{
    const int lane  = threadIdx.x & 63;
    const int wid   = threadIdx.x >> 6;
    const int gwave = blockIdx.x * 4 + wid;
    const int nwaves = gridDim.x * 4;

    const float4* W4 = reinterpret_cast<const float4*>(W);
    const float4 w0 = W4[lane];
    const float4 w1 = W4[64 + lane];
    const float4 w2 = W4[128 + lane];
    const float4 w3 = W4[192 + lane];
    const float bias = bias_p[0];

    float acc = 0.0f;
    for (int s = gwave; s < nspans; s += nwaves) {
        const int   bid = bids[s];
        const int   beg = begins[s] - 1;
        const int   end = ends[s];
        const float t   = targets[s];
        const float4* frow = reinterpret_cast<const float4*>(
            hidden + ((size_t)beg * 16 + (size_t)bid) * FEAT);
        const float4* brow = reinterpret_cast<const float4*>(
            hidden + ((size_t)end * 16 + (size_t)bid) * FEAT + HIDD);
        float d = dot4(frow[lane], w0) + dot4(frow[64 + lane], w1)
                + dot4(brow[lane], w2) + dot4(brow[64 + lane], w3);
        d = wave_reduce(d);
        if (lane == 0) {
            const float z  = d + bias;
            const float p  = 1.0f / (1.0f + expf(-z));
            const float pc = fminf(fmaxf(p, 1e-12f), 1.0f);
            const float qc = fminf(fmaxf(1.0f - p, 1e-12f), 1.0f);
            acc += -(t * logf(pc) + (1.0f - t) * logf(qc));
        }
    }
    __shared__ float sacc[4];
    if (lane == 0) sacc[wid] = acc;
    __syncthreads();
    if (threadIdx.x == 0) {
        float s = 0.0f;
        #pragma unroll
        for (int i = 0; i < 4; ++i) s += sacc[i];
        atomicAdd(out, s * inv_n);
    }
}

extern "C" void kernel_launch(void* const* d_in, const int* in_sizes, int n_in,
                              void* d_out, int out_size, void* d_ws, size_t ws_size,
                              hipStream_t stream) {
    const float* hidden  = (const float*)d_in[0];
    const int*   bids    = (const int*)  d_in[1];
    const int*   begins  = (const int*)  d_in[2];
    const int*   ends    = (const int*)  d_in[3];
    const float* targets = (const float*)d_in[4];
    const float* W       = (const float*)d_in[5];
    const float* b       = (const float*)d_in[6];
    float* out = (float*)d_out;

    const int nspans = in_sizes[1];
    const float inv_n = 1.0f / (float)nspans;
    const int blocks2 = (nspans + K2_BLOCK - 1) / K2_BLOCK;

    const size_t need = ((size_t)2 * NROWS + (size_t)blocks2) * sizeof(float);
    if (ws_size >= need) {
        float* tab      = (float*)d_ws;
        float* partials = tab + 2 * NROWS;
        // K1: exact grid, 2 rows per wave, no loop
        row_dot_kernel<<<NROWS / 8, 256, 0, stream>>>(hidden, W, tab, NROWS);
        // K2: one thread per span, block partials (no atomics)
        span_bce_kernel<<<blocks2, K2_BLOCK, 0, stream>>>(
            tab, bids, begins, ends, targets, b, partials, nspans, NROWS);
        // K3: single block reduces partials, writes out directly
        final_reduce_kernel<<<1, 256, 0, stream>>>(partials, out, blocks2, inv_n);
    } else {
        hipMemsetAsync(out, 0, sizeof(float), stream);
        phrase_cls_fallback<<<2048, 256, 0, stream>>>(
            hidden, bids, begins, ends, targets, W, b, out, nspans, inv_n);
    }
}